// Round 15
// baseline (213.512 us; speedup 1.0000x reference)
//
#include <hip/hip_runtime.h>

typedef unsigned short u16;
typedef __attribute__((ext_vector_type(4))) float f32x4;
typedef __attribute__((ext_vector_type(8))) short short8;
typedef __attribute__((ext_vector_type(4))) unsigned int uv4;
typedef __attribute__((ext_vector_type(4))) float fv4;
typedef __attribute__((ext_vector_type(4))) unsigned short usv4;

#define S_LEN 2048
#define NBLK 128
#define DMODEL 512
#define VOCAB 32000
#define QLEN 2048
#define KVLEN 4096
#define NSPLIT 250   // 32000 vocab / 128-vocab blocks

#define GAS(p) ((const __attribute__((address_space(1))) void*)(const void*)(p))
#define LAS(p) ((__attribute__((address_space(3))) void*)(void*)(p))

__device__ __forceinline__ float bf2f(u16 u){
  union { unsigned int i; float f; } x; x.i = ((unsigned int)u) << 16; return x.f;
}
__device__ __forceinline__ u16 f2bf(float f){
  union { float f; unsigned int i; } x; x.f = f;
  unsigned int r = x.i + 0x7fffu + ((x.i >> 16) & 1u);
  return (u16)(r >> 16);
}

// ---------------- merged weight prep: 1-D grid.
// id < 1024: transpose+cast one 32x32 tile of Wq/Wk/Wv/Wo (f32(512,512) -> bf16 (N,K)).
// id >= 1024: W_lm f32(512,32000) -> bf16 MFMA-fragment-major, coalesced 1KB/wave writes.
__global__ __launch_bounds__(256) void prep_w(const float* __restrict__ Wq, const float* __restrict__ Wk,
                                              const float* __restrict__ Wv, const float* __restrict__ Wo,
                                              const float* __restrict__ Wlm,
                                              u16* __restrict__ WqT, u16* __restrict__ WkT,
                                              u16* __restrict__ WvT, u16* __restrict__ WoT,
                                              u16* __restrict__ Wf){
  __shared__ float tile[64][33];
  int t = threadIdx.x;
  int id = blockIdx.x;
  if (id < 1024){
    const float* in; u16* out;
    switch (id >> 8){
      case 0: in = Wq; out = WqT; break;
      case 1: in = Wk; out = WkT; break;
      case 2: in = Wv; out = WvT; break;
      default: in = Wo; out = WoT; break;
    }
    int rem = id & 255;
    int nb = (rem & 15) * 32, kb = (rem >> 4) * 32;
    int tx = t & 31, ty = t >> 5;
    #pragma unroll
    for (int i = 0; i < 4; i++){
      int r = ty + i * 8;
      tile[r][tx] = in[(size_t)(kb + r) * 512 + nb + tx];
    }
    __syncthreads();
    #pragma unroll
    for (int i = 0; i < 4; i++){
      int r = ty + i * 8;
      out[(size_t)(nb + r) * 512 + kb + tx] = f2bf(tile[tx][r]);
    }
  } else {
    int j = id - 1024;               // 0..7999
    int vb32 = j % 1000, kblk = j / 1000;   // 32 v, 64 k per block
    int tx = t & 31, ty = t >> 5;
    #pragma unroll
    for (int i = 0; i < 8; i++){
      int r = ty + i * 8;
      tile[r][tx] = Wlm[(size_t)(kblk * 64 + r) * VOCAB + vb32 * 32 + tx];
    }
    __syncthreads();
    int w = t >> 6, lane = t & 63;
    int v16sel = w & 1, ktsel = w >> 1;
    int gsel = lane >> 4, li = lane & 15;
    u16 tmp[8];
    #pragma unroll
    for (int jj = 0; jj < 8; jj++)
      tmp[jj] = f2bf(tile[ktsel * 32 + gsel * 8 + jj][v16sel * 16 + li]);
    size_t v16 = vb32 * 2 + v16sel;
    size_t kt32 = kblk * 2 + ktsel;
    *(uv4*)&Wf[((v16 * 16 + kt32) * 64 + lane) * 8] = *(uv4*)tmp;
  }
}

// ---------------- build kv_in (bf16 4096x512): [hidden ; noise_embedding] ----------------
__global__ __launch_bounds__(128) void build_kv(const float* __restrict__ hidden,
                                                const float* __restrict__ embed,
                                                const int* __restrict__ input_ids,
                                                const int* __restrict__ anchors,
                                                const unsigned char* __restrict__ keep,
                                                u16* __restrict__ kvb){
  int row = blockIdx.x;           // 0..4095
  int t = threadIdx.x;            // 0..127
  const float* src;
  if (row < S_LEN){
    src = hidden + (size_t)row * DMODEL;
  } else {
    int q = row - S_LEN;
    int id = 3;                   // MASK_TOKEN_ID
    if ((q & 15) == 0){
      int n = q >> 4;
      if (keep[n]){
        int a = anchors[n]; a = min(max(a, 0), S_LEN - 1);
        id = input_ids[a];
      }
    }
    src = embed + (size_t)id * DMODEL;
  }
  int c = t * 4;
  fv4 v = *(const fv4*)&src[c];
  usv4 o; o[0] = f2bf(v[0]); o[1] = f2bf(v[1]); o[2] = f2bf(v[2]); o[3] = f2bf(v[3]);
  *(usv4*)&kvb[(size_t)row * DMODEL + c] = o;
}

// ---------------- fused q/k/v projection: one launch, 640 blocks of the 128x64 tile ----------------
__global__ __launch_bounds__(256) void qkv_gemm(const u16* __restrict__ kvb,
                                                const u16* __restrict__ WkT,
                                                const u16* __restrict__ WvT,
                                                const u16* __restrict__ WqT,
                                                u16* __restrict__ kb,
                                                u16* __restrict__ vTb,
                                                u16* __restrict__ qb2){
  __shared__ __align__(16) u16 As[2][128 * 64];
  __shared__ __align__(16) u16 Bs[2][64 * 64];
  int id = blockIdx.x;
  const u16* A = kvb; const u16* BT; u16* C; int ldc; int trans = 0;
  int rowbase, colbase;
  if (id < 256){
    BT = WkT; C = kb; ldc = 512;
    rowbase = (id & 31) * 128; colbase = (id >> 5) * 64;
  } else if (id < 512){
    int j = id - 256;
    BT = WvT; C = vTb; ldc = KVLEN; trans = 1;
    rowbase = (j & 31) * 128; colbase = (j >> 5) * 64;
  } else {
    int j = id - 512;
    A = kvb + (size_t)S_LEN * DMODEL;
    BT = WqT; C = qb2; ldc = 512;
    rowbase = (j & 15) * 128; colbase = (j >> 4) * 64;
  }
  int t = threadIdx.x, w = t >> 6, lane = t & 63;
  int g = lane >> 4, li = lane & 15;
  int r0 = t >> 3, cg0 = t & 7;
  int swz = (cg0 ^ (r0 & 7)) << 3;

  auto stageA = [&](u16* dst, int kb_){
    #pragma unroll
    for (int i = 0; i < 4; i++)
      __builtin_amdgcn_global_load_lds(GAS(&A[(size_t)(rowbase + r0 + i * 32) * DMODEL + kb_ + swz]),
                                       LAS(dst + i * 2048 + w * 512), 16, 0, 0);
  };
  auto stageB = [&](u16* dst, int kb_){
    #pragma unroll
    for (int i = 0; i < 2; i++)
      __builtin_amdgcn_global_load_lds(GAS(&BT[(size_t)(colbase + r0 + i * 32) * DMODEL + kb_ + swz]),
                                       LAS(dst + i * 2048 + w * 512), 16, 0, 0);
  };

  f32x4 acc[2][4];
  #pragma unroll
  for (int i = 0; i < 2; i++)
    #pragma unroll
    for (int j = 0; j < 4; j++)
      acc[i][j] = (f32x4){0.f, 0.f, 0.f, 0.f};

  stageA(As[0], 0); stageB(Bs[0], 0);

  for (int kt = 0; kt < 8; kt++){
    u16* curA = As[kt & 1]; u16* curB = Bs[kt & 1];
    if (kt < 7){
      stageA(As[(kt + 1) & 1], (kt + 1) * 64); stageB(Bs[(kt + 1) & 1], (kt + 1) * 64);
      asm volatile("s_waitcnt vmcnt(6)" ::: "memory");
    } else {
      asm volatile("s_waitcnt vmcnt(0)" ::: "memory");
    }
    __builtin_amdgcn_s_barrier();
    #pragma unroll
    for (int ks = 0; ks < 2; ks++){
      short8 af[2], bf[4];
      #pragma unroll
      for (int mf = 0; mf < 2; mf++){
        int row = w * 32 + mf * 16 + li;
        af[mf] = *(const short8*)&curA[row * 64 + (((ks * 4 + g) ^ (li & 7)) << 3)];
      }
      #pragma unroll
      for (int nf = 0; nf < 4; nf++){
        int row = nf * 16 + li;
        bf[nf] = *(const short8*)&curB[row * 64 + (((ks * 4 + g) ^ (li & 7)) << 3)];
      }
      #pragma unroll
      for (int mf = 0; mf < 2; mf++)
        #pragma unroll
        for (int nf = 0; nf < 4; nf++)
          acc[mf][nf] = __builtin_amdgcn_mfma_f32_16x16x32_bf16(af[mf], bf[nf], acc[mf][nf], 0, 0, 0);
    }
    __builtin_amdgcn_s_barrier();
  }

  #pragma unroll
  for (int mf = 0; mf < 2; mf++)
    #pragma unroll
    for (int nf = 0; nf < 4; nf++)
      #pragma unroll
      for (int r = 0; r < 4; r++){
        int row = rowbase + w * 32 + mf * 16 + g * 4 + r;
        int col = colbase + nf * 16 + li;
        u16 vv = f2bf(acc[mf][nf][r]);
        if (trans) C[(size_t)col * ldc + row] = vv;
        else       C[(size_t)row * ldc + col] = vv;
      }
}

// ---------------- o-projection GEMM (128x64 tile, same structure) ----------------
__global__ __launch_bounds__(256) void gemmO(const u16* __restrict__ A,
                                             const u16* __restrict__ BT,
                                             u16* __restrict__ C){
  __shared__ __align__(16) u16 As[2][128 * 64];
  __shared__ __align__(16) u16 Bs[2][64 * 64];
  int t = threadIdx.x, w = t >> 6, lane = t & 63;
  int g = lane >> 4, li = lane & 15;
  int rowbase = blockIdx.x * 128, colbase = blockIdx.y * 64;
  int r0 = t >> 3, cg0 = t & 7;
  int swz = (cg0 ^ (r0 & 7)) << 3;

  auto stageA = [&](u16* dst, int kb_){
    #pragma unroll
    for (int i = 0; i < 4; i++)
      __builtin_amdgcn_global_load_lds(GAS(&A[(size_t)(rowbase + r0 + i * 32) * DMODEL + kb_ + swz]),
                                       LAS(dst + i * 2048 + w * 512), 16, 0, 0);
  };
  auto stageB = [&](u16* dst, int kb_){
    #pragma unroll
    for (int i = 0; i < 2; i++)
      __builtin_amdgcn_global_load_lds(GAS(&BT[(size_t)(colbase + r0 + i * 32) * DMODEL + kb_ + swz]),
                                       LAS(dst + i * 2048 + w * 512), 16, 0, 0);
  };

  f32x4 acc[2][4];
  #pragma unroll
  for (int i = 0; i < 2; i++)
    #pragma unroll
    for (int j = 0; j < 4; j++)
      acc[i][j] = (f32x4){0.f, 0.f, 0.f, 0.f};

  stageA(As[0], 0); stageB(Bs[0], 0);

  for (int kt = 0; kt < 8; kt++){
    u16* curA = As[kt & 1]; u16* curB = Bs[kt & 1];
    if (kt < 7){
      stageA(As[(kt + 1) & 1], (kt + 1) * 64); stageB(Bs[(kt + 1) & 1], (kt + 1) * 64);
      asm volatile("s_waitcnt vmcnt(6)" ::: "memory");
    } else {
      asm volatile("s_waitcnt vmcnt(0)" ::: "memory");
    }
    __builtin_amdgcn_s_barrier();
    #pragma unroll
    for (int ks = 0; ks < 2; ks++){
      short8 af[2], bf[4];
      #pragma unroll
      for (int mf = 0; mf < 2; mf++){
        int row = w * 32 + mf * 16 + li;
        af[mf] = *(const short8*)&curA[row * 64 + (((ks * 4 + g) ^ (li & 7)) << 3)];
      }
      #pragma unroll
      for (int nf = 0; nf < 4; nf++){
        int row = nf * 16 + li;
        bf[nf] = *(const short8*)&curB[row * 64 + (((ks * 4 + g) ^ (li & 7)) << 3)];
      }
      #pragma unroll
      for (int mf = 0; mf < 2; mf++)
        #pragma unroll
        for (int nf = 0; nf < 4; nf++)
          acc[mf][nf] = __builtin_amdgcn_mfma_f32_16x16x32_bf16(af[mf], bf[nf], acc[mf][nf], 0, 0, 0);
    }
    __builtin_amdgcn_s_barrier();
  }

  #pragma unroll
  for (int mf = 0; mf < 2; mf++)
    #pragma unroll
    for (int nf = 0; nf < 4; nf++)
      #pragma unroll
      for (int r = 0; r < 4; r++){
        int row = rowbase + w * 32 + mf * 16 + g * 4 + r;
        int col = colbase + nf * 16 + li;
        C[(size_t)row * DMODEL + col] = f2bf(acc[mf][nf][r]);
      }
}

// ---------------- ob -> fragment-major Of (2MB reformat; 1 wave per 16q x 32k tile) ----------------
// Of[((q16*16 + kt32)*64 + g*16 + li)*8 + j] = ob[q16*16 + li][kt32*32 + g*8 + j]
__global__ __launch_bounds__(256) void ob_frag(const u16* __restrict__ ob, u16* __restrict__ Of){
  int id = blockIdx.x * 4 + (threadIdx.x >> 6);   // 0..2047
  int q16 = id >> 4, kt32 = id & 15;
  int lane = threadIdx.x & 63, g = lane >> 4, li = lane & 15;
  short8 v = *(const short8*)&ob[(size_t)(q16 * 16 + li) * DMODEL + kt32 * 32 + g * 8];
  *(short8*)&Of[((size_t)(q16 * 16 + kt32) * 64 + lane) * 8] = v;
}

// ---------------- MFMA flash attention, NO-MAX softmax (scores bounded ~|10|):
// q pre-scaled by 1/8 at staging (exact for bf16); p = exp(s) directly; no rescale. ----------------
__global__ __launch_bounds__(256) void attn_mfma(const u16* __restrict__ qb,
                                                 const u16* __restrict__ kb,
                                                 const u16* __restrict__ vT,
                                                 const int* __restrict__ anchors,
                                                 const unsigned char* __restrict__ keep,
                                                 u16* __restrict__ attnb){
  int bx = blockIdx.x;
  int n = (bx & 1) ? (NBLK - 1 - (bx >> 1)) : (bx >> 1);   // heavy/light interleave (bijective)
  int h = blockIdx.y;
  int t = threadIdx.x, w = t >> 6, lane = t & 63;
  int g = lane >> 4, li = lane & 15;

  __shared__ __align__(16) u16 q_s[16][72];
  __shared__ __align__(16) u16 p_s[4][16][72];
  __shared__ float o_s[4][16][64];
  __shared__ float l_s[4][16];

  {
    int r = t >> 4, c4 = (t & 15) * 4;
    usv4 v = *(const usv4*)&qb[(size_t)(n * 16 + r) * DMODEL + h * 64 + c4];
    usv4 o;
    #pragma unroll
    for (int j = 0; j < 4; j++) o[j] = f2bf(bf2f(v[j]) * 0.125f);   // exact pow2 scale
    *(usv4*)&q_s[r][c4] = o;
  }
  __syncthreads();

  int anchor = anchors[n];
  bool kp = keep[n] != 0;
  const u16* kh  = kb + h * 64;
  const u16* vTh = vT + (size_t)(h * 64) * KVLEN;

  if (!kp){
    if (w == 0){
      float acc = 0.f;
      const u16* row = vTh + (size_t)lane * KVLEN;
      for (int k2 = 0; k2 < KVLEN; k2 += 8){
        short8 vv = *(const short8*)&row[k2];
        #pragma unroll
        for (int j = 0; j < 8; j++) acc += bf2f((u16)vv[j]);
      }
      acc *= (1.f / 4096.f);
      u16 ov = f2bf(acc);
      for (int r = 0; r < 16; r++)
        attnb[(size_t)(n * 16 + r) * DMODEL + h * 64 + lane] = ov;
    }
    return;
  }

  short8 qa[2];
  #pragma unroll
  for (int ks = 0; ks < 2; ks++)
    qa[ks] = *(const short8*)&q_s[li][ks * 32 + g * 8];

  int nctx = (anchor + 63) >> 6;
  int ntot = nctx + 1;

  f32x4 o_acc[4];
  float l[4];
  #pragma unroll
  for (int i = 0; i < 4; i++){ o_acc[i] = (f32x4){0.f,0.f,0.f,0.f}; l[i] = 0.f; }

  for (int c = w; c < ntot; c += 4){
    bool draft = (c == nctx);
    int kbase = draft ? (S_LEN + n * 16) : c * 64;
    int nk    = draft ? 16 : min(64, anchor - c * 64);

    f32x4 s[4];
    #pragma unroll
    for (int nf = 0; nf < 4; nf++) s[nf] = (f32x4){0.f,0.f,0.f,0.f};
    #pragma unroll
    for (int ks = 0; ks < 2; ks++){
      #pragma unroll
      for (int nf = 0; nf < 4; nf++){
        int krow = min(kbase + nf * 16 + li, KVLEN - 1);
        short8 bfrag = *(const short8*)&kh[(size_t)krow * DMODEL + ks * 32 + g * 8];
        s[nf] = __builtin_amdgcn_mfma_f32_16x16x32_bf16(qa[ks], bfrag, s[nf], 0, 0, 0);
      }
    }

    #pragma unroll
    for (int r = 0; r < 4; r++){
      float ps = 0.f;
      #pragma unroll
      for (int nf = 0; nf < 4; nf++){
        float p = (nf * 16 + li < nk) ? __expf(s[nf][r]) : 0.f;
        ps += p;
        p_s[w][g * 4 + r][nf * 16 + li] = f2bf(p);
      }
      #pragma unroll
      for (int mm = 1; mm < 16; mm <<= 1) ps += __shfl_xor(ps, mm);
      l[r] += ps;
    }

    #pragma unroll
    for (int ks = 0; ks < 2; ks++){
      short8 pa = *(const short8*)&p_s[w][li][ks * 32 + g * 8];
      int kcol = min(kbase + ks * 32 + g * 8, KVLEN - 8);
      #pragma unroll
      for (int nfd = 0; nfd < 4; nfd++){
        short8 vfrag = *(const short8*)&vTh[(size_t)(nfd * 16 + li) * KVLEN + kcol];
        o_acc[nfd] = __builtin_amdgcn_mfma_f32_16x16x32_bf16(pa, vfrag, o_acc[nfd], 0, 0, 0);
      }
    }
  }

  #pragma unroll
  for (int r = 0; r < 4; r++){
    if (li == 0) l_s[w][g * 4 + r] = l[r];
    #pragma unroll
    for (int nfd = 0; nfd < 4; nfd++)
      o_s[w][g * 4 + r][nfd * 16 + li] = o_acc[nfd][r];
  }
  __syncthreads();

  {
    int row = t >> 4, c0 = (t & 15) * 4;
    float L = l_s[0][row] + l_s[1][row] + l_s[2][row] + l_s[3][row];
    float inv = 1.f / L;
    #pragma unroll
    for (int j = 0; j < 4; j++){
      float ov = o_s[0][row][c0 + j] + o_s[1][row][c0 + j] + o_s[2][row][c0 + j] + o_s[3][row][c0 + j];
      attnb[(size_t)(n * 16 + row) * DMODEL + h * 64 + c0 + j] = f2bf(ov * inv);
    }
  }
}

// ---------------- LM head v7: 128q x 128vocab, BOTH operands register-direct from
// fragment-major global (W=Wf, O=Of). ZERO operand LDS, ZERO barriers in K-loop.
// 2x2 wave grid; lane-local stats; tiny LDS only for tcol + cross-wv combine. ----------------
__global__ __launch_bounds__(256) void lm_fused(const u16* __restrict__ Of,
                                                const u16* __restrict__ Wf,
                                                const int* __restrict__ input_ids,
                                                const int* __restrict__ anchors,
                                                float* __restrict__ pl,
                                                float* __restrict__ pt, float* __restrict__ pbv,
                                                int* __restrict__ pbi){
  __shared__ int tcol_s[128];
  __shared__ float cse[2][128], ctv[2][128], cbv[2][128];
  __shared__ int cbi[2][128];

  int L = blockIdx.x;                       // 0..3999
  int T = (L & 7) * 500 + (L >> 3);         // bijective; XCD-contiguous T ranges
  int qblk = T & 15;                        // 0..15 (128 q each)
  int vb = T >> 4;                          // 0..249 vocab block (128 wide)
  int qbase = qblk * 128;
  int vocabbase = vb * 128;
  int t = threadIdx.x, w = t >> 6, lane = t & 63;
  int g = lane >> 4, li = lane & 15;
  int wv = w & 1, wq = w >> 1;              // 2x2 wave grid

  if (t < 128){
    int r = qbase + t; int n = r >> 4, off = r & 15;
    int lab = anchors[n] + off;
    int safe = min(max(lab, 0), S_LEN - 1);
    tcol_s[t] = input_ids[safe];
  }

  // fragment bases: per-(16-row)-block stride = 16 kt32 * 64 lanes * 8 = 8192 elements
  const u16* wbase = Wf + (size_t)(vb * 8 + wv * 4) * 8192 + lane * 8;
  const u16* obase = Of + (size_t)(qblk * 8 + wq * 4) * 8192 + lane * 8;

  f32x4 acc[4][4];                          // [vf][qf]
  #pragma unroll
  for (int i = 0; i < 4; i++)
    #pragma unroll
    for (int j = 0; j < 4; j++)
      acc[i][j] = (f32x4){0.f, 0.f, 0.f, 0.f};

  for (int kt = 0; kt < 16; kt++){
    short8 wfr[4], obf[4];
    #pragma unroll
    for (int vf = 0; vf < 4; vf++)
      wfr[vf] = *(const short8*)(wbase + (size_t)vf * 8192 + kt * 512);
    #pragma unroll
    for (int qf = 0; qf < 4; qf++)
      obf[qf] = *(const short8*)(obase + (size_t)qf * 8192 + kt * 512);
    #pragma unroll
    for (int vf = 0; vf < 4; vf++)
      #pragma unroll
      for (int qf = 0; qf < 4; qf++)
        acc[vf][qf] = __builtin_amdgcn_mfma_f32_16x16x32_bf16(wfr[vf], obf[qf], acc[vf][qf], 0, 0, 0);
  }

  // per-lane stats over this wave's 64-vocab span, per q-column (lane-local)
  #pragma unroll
  for (int qf = 0; qf < 4; qf++){
    int qloc = wq * 64 + qf * 16 + li;
    int tc = tcol_s[qloc] - (vocabbase + wv * 64);
    float se = 0.f, tv = -3e38f, bv = -3e38f; int bi = 0x7fffffff;
    #pragma unroll
    for (int vf = 0; vf < 4; vf++){
      #pragma unroll
      for (int r = 0; r < 4; r++){
        float v = acc[vf][qf][r];
        int pos = vf * 16 + g * 4 + r;
        se += __expf(v);
        if (pos == tc) tv = v;
        if (v > bv){ bv = v; bi = pos; }
      }
    }
    #pragma unroll
    for (int off = 16; off <= 32; off <<= 1){
      se += __shfl_xor(se, off);
      tv = fmaxf(tv, __shfl_xor(tv, off));
      float ob_ = __shfl_xor(bv, off); int oi = __shfl_xor(bi, off);
      if (ob_ > bv || (ob_ == bv && oi < bi)){ bv = ob_; bi = oi; }
    }
    if (g == 0){
      cse[wv][qloc] = se; ctv[wv][qloc] = tv;
      cbv[wv][qloc] = bv; cbi[wv][qloc] = wv * 64 + bi;
    }
  }
  __syncthreads();

  if (t < 128){
    float SE = 0.f, TV = -3e38f, BV = -3e38f; int BI = 0x7fffffff;
    #pragma unroll
    for (int vv = 0; vv < 2; vv++){
      SE += cse[vv][t];
      TV = fmaxf(TV, ctv[vv][t]);
      float v = cbv[vv][t];
      if (v > BV){ BV = v; BI = cbi[vv][t]; }  // vv ascends in vocab: strict > keeps first-max
    }
    size_t idx = (size_t)vb * QLEN + qbase + t;  // [split][row] -> coalesced
    pl[idx] = SE; pt[idx] = TV; pbv[idx] = BV; pbi[idx] = vocabbase + BI;
  }
}

// ---------------- per-row split merge: one wave per row ----------------
__global__ __launch_bounds__(256) void loss_rows(const float* __restrict__ pl,
                                                 const float* __restrict__ pt, const float* __restrict__ pbv,
                                                 const int* __restrict__ pbi,
                                                 const int* __restrict__ input_ids,
                                                 const int* __restrict__ anchors,
                                                 const unsigned char* __restrict__ keep,
                                                 const float* __restrict__ loss_mask,
                                                 float* __restrict__ rowacc){
  int t = threadIdx.x, w = t >> 6, lane = t & 63;
  int row = blockIdx.x * 4 + w;
  float L = 0.f, TV = -3e38f, BV = -3e38f; int BI = 0x7fffffff;
  for (int s = lane; s < NSPLIT; s += 64){
    size_t idx = (size_t)s * QLEN + row;    // [split][row]
    L += pl[idx];
    TV = fmaxf(TV, pt[idx]);
    float bv_ = pbv[idx]; int bi_ = pbi[idx];
    if (bv_ > BV || (bv_ == BV && bi_ < BI)){ BV = bv_; BI = bi_; }
  }
  #pragma unroll
  for (int mm = 1; mm < 64; mm <<= 1){
    L += __shfl_xor(L, mm);
    TV = fmaxf(TV, __shfl_xor(TV, mm));
    float ob = __shfl_xor(BV, mm); int oi = __shfl_xor(BI, mm);
    if (ob > BV || (ob == BV && oi < BI)){ BV = ob; BI = oi; }
  }
  if (lane == 0){
    int n = row >> 4, off = row & 15;
    int lab = anchors[n] + off;
    int valid = (lab < S_LEN) ? 1 : 0;
    int safe = min(max(lab, 0), S_LEN - 1);
    int tgt = input_ids[safe];
    float wgt = (keep[n] ? 1.f : 0.f) * (valid ? 1.f : 0.f) * ((off > 0) ? 1.f : 0.f) * loss_mask[safe];
    float logp = TV - __logf(L);
    rowacc[row * 3 + 0] = -logp * wgt;
    rowacc[row * 3 + 1] = wgt;
    rowacc[row * 3 + 2] = ((BI == tgt) && (wgt > 0.5f)) ? 1.f : 0.f;
  }
}

// ---------------- final sum over rows ----------------
__global__ __launch_bounds__(256) void final_sum(const float* __restrict__ rowacc, float* __restrict__ out){
  int t = threadIdx.x;
  float a = 0.f, b = 0.f, c = 0.f;
  for (int r = t; r < QLEN; r += 256){
    a += rowacc[r * 3 + 0]; b += rowacc[r * 3 + 1]; c += rowacc[r * 3 + 2];
  }
  __shared__ float sa[256], sb[256], sc_[256];
  sa[t] = a; sb[t] = b; sc_[t] = c;
  __syncthreads();
  for (int s = 128; s >= 1; s >>= 1){
    if (t < s){ sa[t] += sa[t + s]; sb[t] += sb[t + s]; sc_[t] += sc_[t + s]; }
    __syncthreads();
  }
  if (t == 0){
    out[0] = sa[0] / (sb[0] + 1e-6f);
    out[1] = sc_[0] / (sb[0] + 1e-6f);
  }
}

// ---------------- host ----------------
extern "C" void kernel_launch(void* const* d_in, const int* in_sizes, int n_in,
                              void* d_out, int out_size, void* d_ws, size_t ws_size,
                              hipStream_t stream) {
  const int*   input_ids = (const int*)  d_in[0];
  const float* hidden    = (const float*)d_in[1];
  const float* loss_mask = (const float*)d_in[2];
  const int*   anchors   = (const int*)  d_in[3];
  const unsigned char* keep = (const unsigned char*)d_in[4];
  const float* embed     = (const float*)d_in[5];
  const float* Wq        = (const float*)d_in[6];
  const float* Wk        = (const float*)d_in[7];
  const float* Wv        = (const float*)d_in[8];
  const float* Wo        = (const float*)d_in[9];
  const float* Wlm       = (const float*)d_in[10];

  char* ws = (char*)d_ws;
  size_t off = 0;
  auto take = [&](size_t bytes) -> char* {
    char* p = ws + off;
    off += (bytes + 255) & ~(size_t)255;
    return p;
  };
  u16* WqT  = (u16*)take((size_t)512 * 512 * 2);
  u16* WkT  = (u16*)take((size_t)512 * 512 * 2);
  u16* WvT  = (u16*)take((size_t)512 * 512 * 2);
  u16* WoT  = (u16*)take((size_t)512 * 512 * 2);
  u16* Wfrag= (u16*)take((size_t)VOCAB * 512 * 2);
  u16* kvb  = (u16*)take((size_t)KVLEN * 512 * 2);
  u16* qb2  = (u16*)take((size_t)QLEN * 512 * 2);
  u16* kb   = (u16*)take((size_t)KVLEN * 512 * 2);
  u16* vTb  = (u16*)take((size_t)512 * KVLEN * 2);
  u16* attnb= (u16*)take((size_t)QLEN * 512 * 2);
  u16* ob   = (u16*)take((size_t)QLEN * 512 * 2);
  u16* Ofrag= (u16*)take((size_t)QLEN * 512 * 2);
  float* pl = (float*)take((size_t)QLEN * NSPLIT * 4);
  float* pt = (float*)take((size_t)QLEN * NSPLIT * 4);
  float* pbv= (float*)take((size_t)QLEN * NSPLIT * 4);
  int*   pbi= (int*)  take((size_t)QLEN * NSPLIT * 4);
  float* rowacc = (float*)take((size_t)QLEN * 3 * 4);

  prep_w<<<9024, 256, 0, stream>>>(Wq, Wk, Wv, Wo, Wlm, WqT, WkT, WvT, WoT, Wfrag);

  build_kv<<<KVLEN, 128, 0, stream>>>(hidden, embed, input_ids, anchors, keep, kvb);

  qkv_gemm<<<640, 256, 0, stream>>>(kvb, WkT, WvT, WqT, kb, vTb, qb2);

  attn_mfma<<<dim3(NBLK, 8), 256, 0, stream>>>(qb2, kb, vTb, anchors, keep, attnb);

  gemmO<<<dim3(16, 8), 256, 0, stream>>>(attnb, WoT, ob);

  ob_frag<<<512, 256, 0, stream>>>(ob, Ofrag);

  lm_fused<<<4000, 256, 0, stream>>>(Ofrag, Wfrag, input_ids, anchors, pl, pt, pbv, pbi);

  loss_rows<<<512, 256, 0, stream>>>(pl, pt, pbv, pbi, input_ids, anchors, keep, loss_mask, rowacc);

  final_sum<<<1, 256, 0, stream>>>(rowacc, (float*)d_out);
}

// Round 16
// 209.374 us; speedup vs baseline: 1.0198x; 1.0198x over previous
//
#include <hip/hip_runtime.h>

typedef unsigned short u16;
typedef __attribute__((ext_vector_type(4))) float f32x4;
typedef __attribute__((ext_vector_type(8))) short short8;
typedef __attribute__((ext_vector_type(4))) unsigned int uv4;
typedef __attribute__((ext_vector_type(4))) float fv4;
typedef __attribute__((ext_vector_type(4))) unsigned short usv4;

#define S_LEN 2048
#define NBLK 128
#define DMODEL 512
#define VOCAB 32000
#define QLEN 2048
#define KVLEN 4096
#define NSPLIT 250   // 32000 vocab / 128-vocab blocks

#define GAS(p) ((const __attribute__((address_space(1))) void*)(const void*)(p))
#define LAS(p) ((__attribute__((address_space(3))) void*)(void*)(p))

__device__ __forceinline__ float bf2f(u16 u){
  union { unsigned int i; float f; } x; x.i = ((unsigned int)u) << 16; return x.f;
}
__device__ __forceinline__ u16 f2bf(float f){
  union { float f; unsigned int i; } x; x.f = f;
  unsigned int r = x.i + 0x7fffu + ((x.i >> 16) & 1u);
  return (u16)(r >> 16);
}

// ---------------- merged weight prep: 1-D grid.
// id < 1024: transpose+cast one 32x32 tile of Wq/Wk/Wv/Wo (f32(512,512) -> bf16 (N,K)).
// id >= 1024: W_lm f32(512,32000) -> bf16 MFMA-fragment-major, coalesced 1KB/wave writes.
__global__ __launch_bounds__(256) void prep_w(const float* __restrict__ Wq, const float* __restrict__ Wk,
                                              const float* __restrict__ Wv, const float* __restrict__ Wo,
                                              const float* __restrict__ Wlm,
                                              u16* __restrict__ WqT, u16* __restrict__ WkT,
                                              u16* __restrict__ WvT, u16* __restrict__ WoT,
                                              u16* __restrict__ Wf){
  __shared__ float tile[64][33];
  int t = threadIdx.x;
  int id = blockIdx.x;
  if (id < 1024){
    const float* in; u16* out;
    switch (id >> 8){
      case 0: in = Wq; out = WqT; break;
      case 1: in = Wk; out = WkT; break;
      case 2: in = Wv; out = WvT; break;
      default: in = Wo; out = WoT; break;
    }
    int rem = id & 255;
    int nb = (rem & 15) * 32, kb = (rem >> 4) * 32;
    int tx = t & 31, ty = t >> 5;
    #pragma unroll
    for (int i = 0; i < 4; i++){
      int r = ty + i * 8;
      tile[r][tx] = in[(size_t)(kb + r) * 512 + nb + tx];
    }
    __syncthreads();
    #pragma unroll
    for (int i = 0; i < 4; i++){
      int r = ty + i * 8;
      out[(size_t)(nb + r) * 512 + kb + tx] = f2bf(tile[tx][r]);
    }
  } else {
    int j = id - 1024;               // 0..7999
    int vb32 = j % 1000, kblk = j / 1000;   // 32 v, 64 k per block
    int tx = t & 31, ty = t >> 5;
    #pragma unroll
    for (int i = 0; i < 8; i++){
      int r = ty + i * 8;
      tile[r][tx] = Wlm[(size_t)(kblk * 64 + r) * VOCAB + vb32 * 32 + tx];
    }
    __syncthreads();
    int w = t >> 6, lane = t & 63;
    int v16sel = w & 1, ktsel = w >> 1;
    int gsel = lane >> 4, li = lane & 15;
    u16 tmp[8];
    #pragma unroll
    for (int jj = 0; jj < 8; jj++)
      tmp[jj] = f2bf(tile[ktsel * 32 + gsel * 8 + jj][v16sel * 16 + li]);
    size_t v16 = vb32 * 2 + v16sel;
    size_t kt32 = kblk * 2 + ktsel;
    *(uv4*)&Wf[((v16 * 16 + kt32) * 64 + lane) * 8] = *(uv4*)tmp;
  }
}

// ---------------- build kv_in (bf16 4096x512): [hidden ; noise_embedding] ----------------
__global__ __launch_bounds__(128) void build_kv(const float* __restrict__ hidden,
                                                const float* __restrict__ embed,
                                                const int* __restrict__ input_ids,
                                                const int* __restrict__ anchors,
                                                const unsigned char* __restrict__ keep,
                                                u16* __restrict__ kvb){
  int row = blockIdx.x;           // 0..4095
  int t = threadIdx.x;            // 0..127
  const float* src;
  if (row < S_LEN){
    src = hidden + (size_t)row * DMODEL;
  } else {
    int q = row - S_LEN;
    int id = 3;                   // MASK_TOKEN_ID
    if ((q & 15) == 0){
      int n = q >> 4;
      if (keep[n]){
        int a = anchors[n]; a = min(max(a, 0), S_LEN - 1);
        id = input_ids[a];
      }
    }
    src = embed + (size_t)id * DMODEL;
  }
  int c = t * 4;
  fv4 v = *(const fv4*)&src[c];
  usv4 o; o[0] = f2bf(v[0]); o[1] = f2bf(v[1]); o[2] = f2bf(v[2]); o[3] = f2bf(v[3]);
  *(usv4*)&kvb[(size_t)row * DMODEL + c] = o;
}

// ---------------- fused q/k/v projection: one launch, 640 blocks of the 128x64 tile ----------------
__global__ __launch_bounds__(256) void qkv_gemm(const u16* __restrict__ kvb,
                                                const u16* __restrict__ WkT,
                                                const u16* __restrict__ WvT,
                                                const u16* __restrict__ WqT,
                                                u16* __restrict__ kb,
                                                u16* __restrict__ vTb,
                                                u16* __restrict__ qb2){
  __shared__ __align__(16) u16 As[2][128 * 64];
  __shared__ __align__(16) u16 Bs[2][64 * 64];
  int id = blockIdx.x;
  const u16* A = kvb; const u16* BT; u16* C; int ldc; int trans = 0;
  int rowbase, colbase;
  if (id < 256){
    BT = WkT; C = kb; ldc = 512;
    rowbase = (id & 31) * 128; colbase = (id >> 5) * 64;
  } else if (id < 512){
    int j = id - 256;
    BT = WvT; C = vTb; ldc = KVLEN; trans = 1;
    rowbase = (j & 31) * 128; colbase = (j >> 5) * 64;
  } else {
    int j = id - 512;
    A = kvb + (size_t)S_LEN * DMODEL;
    BT = WqT; C = qb2; ldc = 512;
    rowbase = (j & 15) * 128; colbase = (j >> 4) * 64;
  }
  int t = threadIdx.x, w = t >> 6, lane = t & 63;
  int g = lane >> 4, li = lane & 15;
  int r0 = t >> 3, cg0 = t & 7;
  int swz = (cg0 ^ (r0 & 7)) << 3;

  auto stageA = [&](u16* dst, int kb_){
    #pragma unroll
    for (int i = 0; i < 4; i++)
      __builtin_amdgcn_global_load_lds(GAS(&A[(size_t)(rowbase + r0 + i * 32) * DMODEL + kb_ + swz]),
                                       LAS(dst + i * 2048 + w * 512), 16, 0, 0);
  };
  auto stageB = [&](u16* dst, int kb_){
    #pragma unroll
    for (int i = 0; i < 2; i++)
      __builtin_amdgcn_global_load_lds(GAS(&BT[(size_t)(colbase + r0 + i * 32) * DMODEL + kb_ + swz]),
                                       LAS(dst + i * 2048 + w * 512), 16, 0, 0);
  };

  f32x4 acc[2][4];
  #pragma unroll
  for (int i = 0; i < 2; i++)
    #pragma unroll
    for (int j = 0; j < 4; j++)
      acc[i][j] = (f32x4){0.f, 0.f, 0.f, 0.f};

  stageA(As[0], 0); stageB(Bs[0], 0);

  for (int kt = 0; kt < 8; kt++){
    u16* curA = As[kt & 1]; u16* curB = Bs[kt & 1];
    if (kt < 7){
      stageA(As[(kt + 1) & 1], (kt + 1) * 64); stageB(Bs[(kt + 1) & 1], (kt + 1) * 64);
      asm volatile("s_waitcnt vmcnt(6)" ::: "memory");
    } else {
      asm volatile("s_waitcnt vmcnt(0)" ::: "memory");
    }
    __builtin_amdgcn_s_barrier();
    #pragma unroll
    for (int ks = 0; ks < 2; ks++){
      short8 af[2], bf[4];
      #pragma unroll
      for (int mf = 0; mf < 2; mf++){
        int row = w * 32 + mf * 16 + li;
        af[mf] = *(const short8*)&curA[row * 64 + (((ks * 4 + g) ^ (li & 7)) << 3)];
      }
      #pragma unroll
      for (int nf = 0; nf < 4; nf++){
        int row = nf * 16 + li;
        bf[nf] = *(const short8*)&curB[row * 64 + (((ks * 4 + g) ^ (li & 7)) << 3)];
      }
      #pragma unroll
      for (int mf = 0; mf < 2; mf++)
        #pragma unroll
        for (int nf = 0; nf < 4; nf++)
          acc[mf][nf] = __builtin_amdgcn_mfma_f32_16x16x32_bf16(af[mf], bf[nf], acc[mf][nf], 0, 0, 0);
    }
    __builtin_amdgcn_s_barrier();
  }

  #pragma unroll
  for (int mf = 0; mf < 2; mf++)
    #pragma unroll
    for (int nf = 0; nf < 4; nf++)
      #pragma unroll
      for (int r = 0; r < 4; r++){
        int row = rowbase + w * 32 + mf * 16 + g * 4 + r;
        int col = colbase + nf * 16 + li;
        u16 vv = f2bf(acc[mf][nf][r]);
        if (trans) C[(size_t)col * ldc + row] = vv;
        else       C[(size_t)row * ldc + col] = vv;
      }
}

// ---------------- o-projection GEMM (128x64 tile, same structure) ----------------
__global__ __launch_bounds__(256) void gemmO(const u16* __restrict__ A,
                                             const u16* __restrict__ BT,
                                             u16* __restrict__ C){
  __shared__ __align__(16) u16 As[2][128 * 64];
  __shared__ __align__(16) u16 Bs[2][64 * 64];
  int t = threadIdx.x, w = t >> 6, lane = t & 63;
  int g = lane >> 4, li = lane & 15;
  int rowbase = blockIdx.x * 128, colbase = blockIdx.y * 64;
  int r0 = t >> 3, cg0 = t & 7;
  int swz = (cg0 ^ (r0 & 7)) << 3;

  auto stageA = [&](u16* dst, int kb_){
    #pragma unroll
    for (int i = 0; i < 4; i++)
      __builtin_amdgcn_global_load_lds(GAS(&A[(size_t)(rowbase + r0 + i * 32) * DMODEL + kb_ + swz]),
                                       LAS(dst + i * 2048 + w * 512), 16, 0, 0);
  };
  auto stageB = [&](u16* dst, int kb_){
    #pragma unroll
    for (int i = 0; i < 2; i++)
      __builtin_amdgcn_global_load_lds(GAS(&BT[(size_t)(colbase + r0 + i * 32) * DMODEL + kb_ + swz]),
                                       LAS(dst + i * 2048 + w * 512), 16, 0, 0);
  };

  f32x4 acc[2][4];
  #pragma unroll
  for (int i = 0; i < 2; i++)
    #pragma unroll
    for (int j = 0; j < 4; j++)
      acc[i][j] = (f32x4){0.f, 0.f, 0.f, 0.f};

  stageA(As[0], 0); stageB(Bs[0], 0);

  for (int kt = 0; kt < 8; kt++){
    u16* curA = As[kt & 1]; u16* curB = Bs[kt & 1];
    if (kt < 7){
      stageA(As[(kt + 1) & 1], (kt + 1) * 64); stageB(Bs[(kt + 1) & 1], (kt + 1) * 64);
      asm volatile("s_waitcnt vmcnt(6)" ::: "memory");
    } else {
      asm volatile("s_waitcnt vmcnt(0)" ::: "memory");
    }
    __builtin_amdgcn_s_barrier();
    #pragma unroll
    for (int ks = 0; ks < 2; ks++){
      short8 af[2], bf[4];
      #pragma unroll
      for (int mf = 0; mf < 2; mf++){
        int row = w * 32 + mf * 16 + li;
        af[mf] = *(const short8*)&curA[row * 64 + (((ks * 4 + g) ^ (li & 7)) << 3)];
      }
      #pragma unroll
      for (int nf = 0; nf < 4; nf++){
        int row = nf * 16 + li;
        bf[nf] = *(const short8*)&curB[row * 64 + (((ks * 4 + g) ^ (li & 7)) << 3)];
      }
      #pragma unroll
      for (int mf = 0; mf < 2; mf++)
        #pragma unroll
        for (int nf = 0; nf < 4; nf++)
          acc[mf][nf] = __builtin_amdgcn_mfma_f32_16x16x32_bf16(af[mf], bf[nf], acc[mf][nf], 0, 0, 0);
    }
    __builtin_amdgcn_s_barrier();
  }

  #pragma unroll
  for (int mf = 0; mf < 2; mf++)
    #pragma unroll
    for (int nf = 0; nf < 4; nf++)
      #pragma unroll
      for (int r = 0; r < 4; r++){
        int row = rowbase + w * 32 + mf * 16 + g * 4 + r;
        int col = colbase + nf * 16 + li;
        C[(size_t)row * DMODEL + col] = f2bf(acc[mf][nf][r]);
      }
}

// ---------------- MFMA flash attention, NO-MAX softmax (scores bounded ~|10|):
// q pre-scaled by 1/8 at staging (exact for bf16); p = exp(s) directly; no rescale. ----------------
__global__ __launch_bounds__(256) void attn_mfma(const u16* __restrict__ qb,
                                                 const u16* __restrict__ kb,
                                                 const u16* __restrict__ vT,
                                                 const int* __restrict__ anchors,
                                                 const unsigned char* __restrict__ keep,
                                                 u16* __restrict__ attnb){
  int bx = blockIdx.x;
  int n = (bx & 1) ? (NBLK - 1 - (bx >> 1)) : (bx >> 1);   // heavy/light interleave (bijective)
  int h = blockIdx.y;
  int t = threadIdx.x, w = t >> 6, lane = t & 63;
  int g = lane >> 4, li = lane & 15;

  __shared__ __align__(16) u16 q_s[16][72];
  __shared__ __align__(16) u16 p_s[4][16][72];
  __shared__ float o_s[4][16][64];
  __shared__ float l_s[4][16];

  {
    int r = t >> 4, c4 = (t & 15) * 4;
    usv4 v = *(const usv4*)&qb[(size_t)(n * 16 + r) * DMODEL + h * 64 + c4];
    usv4 o;
    #pragma unroll
    for (int j = 0; j < 4; j++) o[j] = f2bf(bf2f(v[j]) * 0.125f);   // exact pow2 scale
    *(usv4*)&q_s[r][c4] = o;
  }
  __syncthreads();

  int anchor = anchors[n];
  bool kp = keep[n] != 0;
  const u16* kh  = kb + h * 64;
  const u16* vTh = vT + (size_t)(h * 64) * KVLEN;

  if (!kp){
    if (w == 0){
      float acc = 0.f;
      const u16* row = vTh + (size_t)lane * KVLEN;
      for (int k2 = 0; k2 < KVLEN; k2 += 8){
        short8 vv = *(const short8*)&row[k2];
        #pragma unroll
        for (int j = 0; j < 8; j++) acc += bf2f((u16)vv[j]);
      }
      acc *= (1.f / 4096.f);
      u16 ov = f2bf(acc);
      for (int r = 0; r < 16; r++)
        attnb[(size_t)(n * 16 + r) * DMODEL + h * 64 + lane] = ov;
    }
    return;
  }

  short8 qa[2];
  #pragma unroll
  for (int ks = 0; ks < 2; ks++)
    qa[ks] = *(const short8*)&q_s[li][ks * 32 + g * 8];

  int nctx = (anchor + 63) >> 6;
  int ntot = nctx + 1;

  f32x4 o_acc[4];
  float l[4];
  #pragma unroll
  for (int i = 0; i < 4; i++){ o_acc[i] = (f32x4){0.f,0.f,0.f,0.f}; l[i] = 0.f; }

  for (int c = w; c < ntot; c += 4){
    bool draft = (c == nctx);
    int kbase = draft ? (S_LEN + n * 16) : c * 64;
    int nk    = draft ? 16 : min(64, anchor - c * 64);

    f32x4 s[4];
    #pragma unroll
    for (int nf = 0; nf < 4; nf++) s[nf] = (f32x4){0.f,0.f,0.f,0.f};
    #pragma unroll
    for (int ks = 0; ks < 2; ks++){
      #pragma unroll
      for (int nf = 0; nf < 4; nf++){
        int krow = min(kbase + nf * 16 + li, KVLEN - 1);
        short8 bfrag = *(const short8*)&kh[(size_t)krow * DMODEL + ks * 32 + g * 8];
        s[nf] = __builtin_amdgcn_mfma_f32_16x16x32_bf16(qa[ks], bfrag, s[nf], 0, 0, 0);
      }
    }

    #pragma unroll
    for (int r = 0; r < 4; r++){
      float ps = 0.f;
      #pragma unroll
      for (int nf = 0; nf < 4; nf++){
        float p = (nf * 16 + li < nk) ? __expf(s[nf][r]) : 0.f;
        ps += p;
        p_s[w][g * 4 + r][nf * 16 + li] = f2bf(p);
      }
      #pragma unroll
      for (int mm = 1; mm < 16; mm <<= 1) ps += __shfl_xor(ps, mm);
      l[r] += ps;
    }

    #pragma unroll
    for (int ks = 0; ks < 2; ks++){
      short8 pa = *(const short8*)&p_s[w][li][ks * 32 + g * 8];
      int kcol = min(kbase + ks * 32 + g * 8, KVLEN - 8);
      #pragma unroll
      for (int nfd = 0; nfd < 4; nfd++){
        short8 vfrag = *(const short8*)&vTh[(size_t)(nfd * 16 + li) * KVLEN + kcol];
        o_acc[nfd] = __builtin_amdgcn_mfma_f32_16x16x32_bf16(pa, vfrag, o_acc[nfd], 0, 0, 0);
      }
    }
  }

  #pragma unroll
  for (int r = 0; r < 4; r++){
    if (li == 0) l_s[w][g * 4 + r] = l[r];
    #pragma unroll
    for (int nfd = 0; nfd < 4; nfd++)
      o_s[w][g * 4 + r][nfd * 16 + li] = o_acc[nfd][r];
  }
  __syncthreads();

  {
    int row = t >> 4, c0 = (t & 15) * 4;
    float L = l_s[0][row] + l_s[1][row] + l_s[2][row] + l_s[3][row];
    float inv = 1.f / L;
    #pragma unroll
    for (int j = 0; j < 4; j++){
      float ov = o_s[0][row][c0 + j] + o_s[1][row][c0 + j] + o_s[2][row][c0 + j] + o_s[3][row][c0 + j];
      attnb[(size_t)(n * 16 + row) * DMODEL + h * 64 + c0 + j] = f2bf(ov * inv);
    }
  }
}

// ---------------- LM head (R13 config — empirical optimum): 128q x 128vocab, BK=64
// (8 iters, 16 barriers); W fragments DIRECT from fragment-major global; O in LDS
// ([128][64] dbuf, proven swizzle, gload_lds); counted vmcnt(12); 2x2 wave grid;
// lane-local stats; scratch aliased onto Ob. ----------------
__global__ __launch_bounds__(256) void lm_fused(const u16* __restrict__ obp,
                                                const u16* __restrict__ Wf,
                                                const int* __restrict__ input_ids,
                                                const int* __restrict__ anchors,
                                                float* __restrict__ pl,
                                                float* __restrict__ pt, float* __restrict__ pbv,
                                                int* __restrict__ pbi){
  __shared__ __align__(16) u16 Ob[2][128 * 64];
  __shared__ int tcol_s[128];

  int L = blockIdx.x;                       // 0..3999
  int T = (L & 7) * 500 + (L >> 3);         // bijective; XCD-contiguous T ranges
  int qbase = (T & 15) * 128;               // q fastest within an XCD -> W slice hot in its L2
  int vb = T >> 4;                          // 0..249 vocab block (128 wide)
  int vocabbase = vb * 128;
  int t = threadIdx.x, w = t >> 6, lane = t & 63;
  int g = lane >> 4, li = lane & 15;
  int wv = w & 1, wq = w >> 1;              // 2x2 wave grid

  if (t < 128){
    int r = qbase + t; int n = r >> 4, off = r & 15;
    int lab = anchors[n] + off;
    int safe = min(max(lab, 0), S_LEN - 1);
    tcol_s[t] = input_ids[safe];
  }

  int r0 = t >> 3, cg0 = t & 7;
  int swz = (cg0 ^ (r0 & 7)) << 3;
  auto stageO = [&](u16* odst, int kt){
    #pragma unroll
    for (int i = 0; i < 4; i++)
      __builtin_amdgcn_global_load_lds(GAS(&obp[(size_t)(qbase + r0 + i * 32) * DMODEL + kt * 64 + swz]),
                                       LAS(odst + i * 2048 + w * 512), 16, 0, 0);
  };
  const u16* wbase = Wf + ((size_t)(vb * 8 + wv * 4) * 16) * 512 + lane * 8;

  f32x4 acc[4][4];                          // [vf][qf]
  #pragma unroll
  for (int i = 0; i < 4; i++)
    #pragma unroll
    for (int j = 0; j < 4; j++)
      acc[i][j] = (f32x4){0.f, 0.f, 0.f, 0.f};

  stageO(Ob[0], 0);

  for (int kt = 0; kt < 8; kt++){
    const u16* curO = Ob[kt & 1];
    short8 wfr[2][4];
    if (kt < 7){
      stageO(Ob[(kt + 1) & 1], kt + 1);     // 4 vmem
      #pragma unroll
      for (int ks = 0; ks < 2; ks++)
        #pragma unroll
        for (int vf = 0; vf < 4; vf++)      // 8 vmem (direct global, L2-resident)
          wfr[ks][vf] = *(const short8*)(wbase + ((size_t)(vf * 16 + kt * 2 + ks) * 64) * 8);
      asm volatile("s_waitcnt vmcnt(12)" ::: "memory");  // stageO(kt) landed; 12 newer in flight
    } else {
      #pragma unroll
      for (int ks = 0; ks < 2; ks++)
        #pragma unroll
        for (int vf = 0; vf < 4; vf++)
          wfr[ks][vf] = *(const short8*)(wbase + ((size_t)(vf * 16 + kt * 2 + ks) * 64) * 8);
      asm volatile("s_waitcnt vmcnt(8)" ::: "memory");   // stageO(7) landed
    }
    __builtin_amdgcn_s_barrier();           // all waves: O(kt) visible
    __builtin_amdgcn_s_setprio(1);
    #pragma unroll
    for (int ks = 0; ks < 2; ks++){
      short8 obf[4];
      #pragma unroll
      for (int qf = 0; qf < 4; qf++)
        obf[qf] = *(const short8*)&curO[(wq * 64 + qf * 16 + li) * 64 + (((ks * 4 + g) ^ (li & 7)) << 3)];
      #pragma unroll
      for (int vf = 0; vf < 4; vf++)
        #pragma unroll
        for (int qf = 0; qf < 4; qf++)
          acc[vf][qf] = __builtin_amdgcn_mfma_f32_16x16x32_bf16(wfr[ks][vf], obf[qf], acc[vf][qf], 0, 0, 0);
    }
    __builtin_amdgcn_s_setprio(0);
    __builtin_amdgcn_s_barrier();           // all waves done reading Ob[kt&1]
  }
  __syncthreads();                          // before aliasing Ob as scratch

  float* cse = (float*)&Ob[0][0];           // [2][128]
  float* ctv = (float*)&Ob[0][512];
  float* cbv = (float*)&Ob[0][1024];
  int*   cbi = (int*)  &Ob[0][1536];

  #pragma unroll
  for (int qf = 0; qf < 4; qf++){
    int qloc = wq * 64 + qf * 16 + li;
    int tc = tcol_s[qloc] - (vocabbase + wv * 64);
    float se = 0.f, tv = -3e38f, bv = -3e38f; int bi = 0x7fffffff;
    #pragma unroll
    for (int vf = 0; vf < 4; vf++){
      #pragma unroll
      for (int r = 0; r < 4; r++){
        float v = acc[vf][qf][r];
        int pos = vf * 16 + g * 4 + r;
        se += __expf(v);
        if (pos == tc) tv = v;
        if (v > bv){ bv = v; bi = pos; }
      }
    }
    #pragma unroll
    for (int off = 16; off <= 32; off <<= 1){
      se += __shfl_xor(se, off);
      tv = fmaxf(tv, __shfl_xor(tv, off));
      float ob_ = __shfl_xor(bv, off); int oi = __shfl_xor(bi, off);
      if (ob_ > bv || (ob_ == bv && oi < bi)){ bv = ob_; bi = oi; }
    }
    if (g == 0){
      cse[wv * 128 + qloc] = se; ctv[wv * 128 + qloc] = tv;
      cbv[wv * 128 + qloc] = bv; cbi[wv * 128 + qloc] = wv * 64 + bi;
    }
  }
  __syncthreads();

  if (t < 128){
    float SE = 0.f, TV = -3e38f, BV = -3e38f; int BI = 0x7fffffff;
    #pragma unroll
    for (int vv = 0; vv < 2; vv++){
      SE += cse[vv * 128 + t];
      TV = fmaxf(TV, ctv[vv * 128 + t]);
      float v = cbv[vv * 128 + t];
      if (v > BV){ BV = v; BI = cbi[vv * 128 + t]; }  // vv ascends in vocab: strict > keeps first-max
    }
    size_t idx = (size_t)vb * QLEN + qbase + t;       // [split][row] -> coalesced
    pl[idx] = SE; pt[idx] = TV; pbv[idx] = BV; pbi[idx] = vocabbase + BI;
  }
}

// ---------------- per-row split merge + global atomic accumulation ----------------
__global__ __launch_bounds__(256) void loss_rows(const float* __restrict__ pl,
                                                 const float* __restrict__ pt, const float* __restrict__ pbv,
                                                 const int* __restrict__ pbi,
                                                 const int* __restrict__ input_ids,
                                                 const int* __restrict__ anchors,
                                                 const unsigned char* __restrict__ keep,
                                                 const float* __restrict__ loss_mask,
                                                 float* __restrict__ acc3){
  int t = threadIdx.x, w = t >> 6, lane = t & 63;
  int row = blockIdx.x * 4 + w;
  float L = 0.f, TV = -3e38f, BV = -3e38f; int BI = 0x7fffffff;
  for (int s = lane; s < NSPLIT; s += 64){
    size_t idx = (size_t)s * QLEN + row;    // [split][row]
    L += pl[idx];
    TV = fmaxf(TV, pt[idx]);
    float bv_ = pbv[idx]; int bi_ = pbi[idx];
    if (bv_ > BV || (bv_ == BV && bi_ < BI)){ BV = bv_; BI = bi_; }
  }
  #pragma unroll
  for (int mm = 1; mm < 64; mm <<= 1){
    L += __shfl_xor(L, mm);
    TV = fmaxf(TV, __shfl_xor(TV, mm));
    float ob = __shfl_xor(BV, mm); int oi = __shfl_xor(BI, mm);
    if (ob > BV || (ob == BV && oi < BI)){ BV = ob; BI = oi; }
  }
  if (lane == 0){
    int n = row >> 4, off = row & 15;
    int lab = anchors[n] + off;
    int valid = (lab < S_LEN) ? 1 : 0;
    int safe = min(max(lab, 0), S_LEN - 1);
    int tgt = input_ids[safe];
    float wgt = (keep[n] ? 1.f : 0.f) * (valid ? 1.f : 0.f) * ((off > 0) ? 1.f : 0.f) * loss_mask[safe];
    float logp = TV - __logf(L);
    if (wgt != 0.f){
      atomicAdd(&acc3[0], -logp * wgt);
      atomicAdd(&acc3[1], wgt);
      if ((BI == tgt)) atomicAdd(&acc3[2], 1.f);
    }
  }
}

// ---------------- final: trivial divide ----------------
__global__ void final_div(const float* __restrict__ acc3, float* __restrict__ out){
  float wsum = acc3[1] + 1e-6f;
  out[0] = acc3[0] / wsum;
  out[1] = acc3[2] / wsum;
}

// ---------------- host ----------------
extern "C" void kernel_launch(void* const* d_in, const int* in_sizes, int n_in,
                              void* d_out, int out_size, void* d_ws, size_t ws_size,
                              hipStream_t stream) {
  const int*   input_ids = (const int*)  d_in[0];
  const float* hidden    = (const float*)d_in[1];
  const float* loss_mask = (const float*)d_in[2];
  const int*   anchors   = (const int*)  d_in[3];
  const unsigned char* keep = (const unsigned char*)d_in[4];
  const float* embed     = (const float*)d_in[5];
  const float* Wq        = (const float*)d_in[6];
  const float* Wk        = (const float*)d_in[7];
  const float* Wv        = (const float*)d_in[8];
  const float* Wo        = (const float*)d_in[9];
  const float* Wlm       = (const float*)d_in[10];

  char* ws = (char*)d_ws;
  size_t off = 0;
  auto take = [&](size_t bytes) -> char* {
    char* p = ws + off;
    off += (bytes + 255) & ~(size_t)255;
    return p;
  };
  u16* WqT  = (u16*)take((size_t)512 * 512 * 2);
  u16* WkT  = (u16*)take((size_t)512 * 512 * 2);
  u16* WvT  = (u16*)take((size_t)512 * 512 * 2);
  u16* WoT  = (u16*)take((size_t)512 * 512 * 2);
  u16* Wfrag= (u16*)take((size_t)VOCAB * 512 * 2);
  u16* kvb  = (u16*)take((size_t)KVLEN * 512 * 2);
  u16* qb2  = (u16*)take((size_t)QLEN * 512 * 2);
  u16* kb   = (u16*)take((size_t)KVLEN * 512 * 2);
  u16* vTb  = (u16*)take((size_t)512 * KVLEN * 2);
  u16* attnb= (u16*)take((size_t)QLEN * 512 * 2);
  u16* ob   = (u16*)take((size_t)QLEN * 512 * 2);
  float* pl = (float*)take((size_t)QLEN * NSPLIT * 4);
  float* pt = (float*)take((size_t)QLEN * NSPLIT * 4);
  float* pbv= (float*)take((size_t)QLEN * NSPLIT * 4);
  int*   pbi= (int*)  take((size_t)QLEN * NSPLIT * 4);
  float* acc3 = (float*)take(3 * 4);

  hipMemsetAsync(acc3, 0, 3 * 4, stream);

  prep_w<<<9024, 256, 0, stream>>>(Wq, Wk, Wv, Wo, Wlm, WqT, WkT, WvT, WoT, Wfrag);

  build_kv<<<KVLEN, 128, 0, stream>>>(hidden, embed, input_ids, anchors, keep, kvb);

  qkv_gemm<<<640, 256, 0, stream>>>(kvb, WkT, WvT, WqT, kb, vTb, qb2);

  attn_mfma<<<dim3(NBLK, 8), 256, 0, stream>>>(qb2, kb, vTb, anchors, keep, attnb);

  gemmO<<<dim3(16, 8), 256, 0, stream>>>(attnb, WoT, ob);

  lm_fused<<<4000, 256, 0, stream>>>(ob, Wfrag, input_ids, anchors, pl, pt, pbv, pbi);

  loss_rows<<<512, 256, 0, stream>>>(pl, pt, pbv, pbi, input_ids, anchors, keep, loss_mask, acc3);

  final_div<<<1, 1, 0, stream>>>(acc3, (float*)d_out);
}

// Round 17
// 195.606 us; speedup vs baseline: 1.0915x; 1.0704x over previous
//
#include <hip/hip_runtime.h>

typedef unsigned short u16;
typedef __attribute__((ext_vector_type(4))) float f32x4;
typedef __attribute__((ext_vector_type(8))) short short8;
typedef __attribute__((ext_vector_type(4))) unsigned int uv4;
typedef __attribute__((ext_vector_type(4))) float fv4;
typedef __attribute__((ext_vector_type(4))) unsigned short usv4;

#define S_LEN 2048
#define NBLK 128
#define DMODEL 512
#define VOCAB 32000
#define QLEN 2048
#define KVLEN 4096
#define NSPLIT 250   // 32000 vocab / 128-vocab blocks

#define GAS(p) ((const __attribute__((address_space(1))) void*)(const void*)(p))
#define LAS(p) ((__attribute__((address_space(3))) void*)(void*)(p))

__device__ __forceinline__ float bf2f(u16 u){
  union { unsigned int i; float f; } x; x.i = ((unsigned int)u) << 16; return x.f;
}
__device__ __forceinline__ u16 f2bf(float f){
  union { float f; unsigned int i; } x; x.f = f;
  unsigned int r = x.i + 0x7fffu + ((x.i >> 16) & 1u);
  return (u16)(r >> 16);
}

// ---------------- merged prep: weights + kv build, 1-D grid (11072 blocks).
// id < 1024:           transpose+cast 32x32 tile of Wq/Wk/Wv/Wo.
// 1024 <= id < 9024:   W_lm -> bf16 MFMA-fragment-major (coalesced 1KB/wave writes).
// id >= 9024:          build kv_in (2 rows per block, 256 threads).
__global__ __launch_bounds__(256) void prep_all(const float* __restrict__ Wq, const float* __restrict__ Wk,
                                                const float* __restrict__ Wv, const float* __restrict__ Wo,
                                                const float* __restrict__ Wlm,
                                                const float* __restrict__ hidden,
                                                const float* __restrict__ embed,
                                                const int* __restrict__ input_ids,
                                                const int* __restrict__ anchors,
                                                const unsigned char* __restrict__ keep,
                                                u16* __restrict__ WqT, u16* __restrict__ WkT,
                                                u16* __restrict__ WvT, u16* __restrict__ WoT,
                                                u16* __restrict__ Wf,
                                                u16* __restrict__ kvb){
  __shared__ float tile[64][33];
  int t = threadIdx.x;
  int id = blockIdx.x;
  if (id < 1024){
    const float* in; u16* out;
    switch (id >> 8){
      case 0: in = Wq; out = WqT; break;
      case 1: in = Wk; out = WkT; break;
      case 2: in = Wv; out = WvT; break;
      default: in = Wo; out = WoT; break;
    }
    int rem = id & 255;
    int nb = (rem & 15) * 32, kb = (rem >> 4) * 32;
    int tx = t & 31, ty = t >> 5;
    #pragma unroll
    for (int i = 0; i < 4; i++){
      int r = ty + i * 8;
      tile[r][tx] = in[(size_t)(kb + r) * 512 + nb + tx];
    }
    __syncthreads();
    #pragma unroll
    for (int i = 0; i < 4; i++){
      int r = ty + i * 8;
      out[(size_t)(nb + r) * 512 + kb + tx] = f2bf(tile[tx][r]);
    }
  } else if (id < 9024){
    int j = id - 1024;               // 0..7999
    int vb32 = j % 1000, kblk = j / 1000;   // 32 v, 64 k per block
    int tx = t & 31, ty = t >> 5;
    #pragma unroll
    for (int i = 0; i < 8; i++){
      int r = ty + i * 8;
      tile[r][tx] = Wlm[(size_t)(kblk * 64 + r) * VOCAB + vb32 * 32 + tx];
    }
    __syncthreads();
    int w = t >> 6, lane = t & 63;
    int v16sel = w & 1, ktsel = w >> 1;
    int gsel = lane >> 4, li = lane & 15;
    u16 tmp[8];
    #pragma unroll
    for (int jj = 0; jj < 8; jj++)
      tmp[jj] = f2bf(tile[ktsel * 32 + gsel * 8 + jj][v16sel * 16 + li]);
    size_t v16 = vb32 * 2 + v16sel;
    size_t kt32 = kblk * 2 + ktsel;
    *(uv4*)&Wf[((v16 * 16 + kt32) * 64 + lane) * 8] = *(uv4*)tmp;
  } else {
    int j2 = id - 9024;              // 0..2047; 2 rows per block
    int row = j2 * 2 + (t >> 7);
    int tl = t & 127;
    const float* src;
    if (row < S_LEN){
      src = hidden + (size_t)row * DMODEL;
    } else {
      int q = row - S_LEN;
      int tok = 3;                   // MASK_TOKEN_ID
      if ((q & 15) == 0){
        int n = q >> 4;
        if (keep[n]){
          int a = anchors[n]; a = min(max(a, 0), S_LEN - 1);
          tok = input_ids[a];
        }
      }
      src = embed + (size_t)tok * DMODEL;
    }
    int c = tl * 4;
    fv4 v = *(const fv4*)&src[c];
    usv4 o; o[0] = f2bf(v[0]); o[1] = f2bf(v[1]); o[2] = f2bf(v[2]); o[3] = f2bf(v[3]);
    *(usv4*)&kvb[(size_t)row * DMODEL + c] = o;
  }
}

// ---------------- fused q/k/v projection: one launch, 640 blocks of the 128x64 tile ----------------
__global__ __launch_bounds__(256) void qkv_gemm(const u16* __restrict__ kvb,
                                                const u16* __restrict__ WkT,
                                                const u16* __restrict__ WvT,
                                                const u16* __restrict__ WqT,
                                                u16* __restrict__ kb,
                                                u16* __restrict__ vTb,
                                                u16* __restrict__ qb2){
  __shared__ __align__(16) u16 As[2][128 * 64];
  __shared__ __align__(16) u16 Bs[2][64 * 64];
  int id = blockIdx.x;
  const u16* A = kvb; const u16* BT; u16* C; int ldc; int trans = 0;
  int rowbase, colbase;
  if (id < 256){
    BT = WkT; C = kb; ldc = 512;
    rowbase = (id & 31) * 128; colbase = (id >> 5) * 64;
  } else if (id < 512){
    int j = id - 256;
    BT = WvT; C = vTb; ldc = KVLEN; trans = 1;
    rowbase = (j & 31) * 128; colbase = (j >> 5) * 64;
  } else {
    int j = id - 512;
    A = kvb + (size_t)S_LEN * DMODEL;
    BT = WqT; C = qb2; ldc = 512;
    rowbase = (j & 15) * 128; colbase = (j >> 4) * 64;
  }
  int t = threadIdx.x, w = t >> 6, lane = t & 63;
  int g = lane >> 4, li = lane & 15;
  int r0 = t >> 3, cg0 = t & 7;
  int swz = (cg0 ^ (r0 & 7)) << 3;

  auto stageA = [&](u16* dst, int kb_){
    #pragma unroll
    for (int i = 0; i < 4; i++)
      __builtin_amdgcn_global_load_lds(GAS(&A[(size_t)(rowbase + r0 + i * 32) * DMODEL + kb_ + swz]),
                                       LAS(dst + i * 2048 + w * 512), 16, 0, 0);
  };
  auto stageB = [&](u16* dst, int kb_){
    #pragma unroll
    for (int i = 0; i < 2; i++)
      __builtin_amdgcn_global_load_lds(GAS(&BT[(size_t)(colbase + r0 + i * 32) * DMODEL + kb_ + swz]),
                                       LAS(dst + i * 2048 + w * 512), 16, 0, 0);
  };

  f32x4 acc[2][4];
  #pragma unroll
  for (int i = 0; i < 2; i++)
    #pragma unroll
    for (int j = 0; j < 4; j++)
      acc[i][j] = (f32x4){0.f, 0.f, 0.f, 0.f};

  stageA(As[0], 0); stageB(Bs[0], 0);

  for (int kt = 0; kt < 8; kt++){
    u16* curA = As[kt & 1]; u16* curB = Bs[kt & 1];
    if (kt < 7){
      stageA(As[(kt + 1) & 1], (kt + 1) * 64); stageB(Bs[(kt + 1) & 1], (kt + 1) * 64);
      asm volatile("s_waitcnt vmcnt(6)" ::: "memory");
    } else {
      asm volatile("s_waitcnt vmcnt(0)" ::: "memory");
    }
    __builtin_amdgcn_s_barrier();
    #pragma unroll
    for (int ks = 0; ks < 2; ks++){
      short8 af[2], bf[4];
      #pragma unroll
      for (int mf = 0; mf < 2; mf++){
        int row = w * 32 + mf * 16 + li;
        af[mf] = *(const short8*)&curA[row * 64 + (((ks * 4 + g) ^ (li & 7)) << 3)];
      }
      #pragma unroll
      for (int nf = 0; nf < 4; nf++){
        int row = nf * 16 + li;
        bf[nf] = *(const short8*)&curB[row * 64 + (((ks * 4 + g) ^ (li & 7)) << 3)];
      }
      #pragma unroll
      for (int mf = 0; mf < 2; mf++)
        #pragma unroll
        for (int nf = 0; nf < 4; nf++)
          acc[mf][nf] = __builtin_amdgcn_mfma_f32_16x16x32_bf16(af[mf], bf[nf], acc[mf][nf], 0, 0, 0);
    }
    __builtin_amdgcn_s_barrier();
  }

  #pragma unroll
  for (int mf = 0; mf < 2; mf++)
    #pragma unroll
    for (int nf = 0; nf < 4; nf++)
      #pragma unroll
      for (int r = 0; r < 4; r++){
        int row = rowbase + w * 32 + mf * 16 + g * 4 + r;
        int col = colbase + nf * 16 + li;
        u16 vv = f2bf(acc[mf][nf][r]);
        if (trans) C[(size_t)col * ldc + row] = vv;
        else       C[(size_t)row * ldc + col] = vv;
      }
}

// ---------------- o-projection GEMM: 64x64 tile, grid (32,8)=256 blocks (fills all CUs) ----------------
__global__ __launch_bounds__(256) void gemmO(const u16* __restrict__ A,
                                             const u16* __restrict__ BT,
                                             u16* __restrict__ C){
  __shared__ __align__(16) u16 As[2][64 * 64];
  __shared__ __align__(16) u16 Bs[2][64 * 64];
  int t = threadIdx.x, w = t >> 6, lane = t & 63;
  int g = lane >> 4, li = lane & 15;
  int rowbase = blockIdx.x * 64, colbase = blockIdx.y * 64;
  int r0 = t >> 3, cg0 = t & 7;
  int swz = (cg0 ^ (r0 & 7)) << 3;

  auto stageA = [&](u16* dst, int kb_){
    #pragma unroll
    for (int i = 0; i < 2; i++)
      __builtin_amdgcn_global_load_lds(GAS(&A[(size_t)(rowbase + r0 + i * 32) * DMODEL + kb_ + swz]),
                                       LAS(dst + i * 2048 + w * 512), 16, 0, 0);
  };
  auto stageB = [&](u16* dst, int kb_){
    #pragma unroll
    for (int i = 0; i < 2; i++)
      __builtin_amdgcn_global_load_lds(GAS(&BT[(size_t)(colbase + r0 + i * 32) * DMODEL + kb_ + swz]),
                                       LAS(dst + i * 2048 + w * 512), 16, 0, 0);
  };

  f32x4 acc[4];
  #pragma unroll
  for (int j = 0; j < 4; j++) acc[j] = (f32x4){0.f, 0.f, 0.f, 0.f};

  stageA(As[0], 0); stageB(Bs[0], 0);

  for (int kt = 0; kt < 8; kt++){
    u16* curA = As[kt & 1]; u16* curB = Bs[kt & 1];
    if (kt < 7){
      stageA(As[(kt + 1) & 1], (kt + 1) * 64); stageB(Bs[(kt + 1) & 1], (kt + 1) * 64);
      asm volatile("s_waitcnt vmcnt(4)" ::: "memory");
    } else {
      asm volatile("s_waitcnt vmcnt(0)" ::: "memory");
    }
    __builtin_amdgcn_s_barrier();
    #pragma unroll
    for (int ks = 0; ks < 2; ks++){
      short8 af;
      {
        int row = w * 16 + li;
        af = *(const short8*)&curA[row * 64 + (((ks * 4 + g) ^ (li & 7)) << 3)];
      }
      short8 bf[4];
      #pragma unroll
      for (int nf = 0; nf < 4; nf++){
        int row = nf * 16 + li;
        bf[nf] = *(const short8*)&curB[row * 64 + (((ks * 4 + g) ^ (li & 7)) << 3)];
      }
      #pragma unroll
      for (int nf = 0; nf < 4; nf++)
        acc[nf] = __builtin_amdgcn_mfma_f32_16x16x32_bf16(af, bf[nf], acc[nf], 0, 0, 0);
    }
    __builtin_amdgcn_s_barrier();
  }

  #pragma unroll
  for (int nf = 0; nf < 4; nf++)
    #pragma unroll
    for (int r = 0; r < 4; r++){
      int row = rowbase + w * 16 + g * 4 + r;
      int col = colbase + nf * 16 + li;
      C[(size_t)row * DMODEL + col] = f2bf(acc[nf][r]);
    }
}

// ---------------- MFMA flash attention, NO-MAX softmax + DEFERRED l-reduction ----------------
__global__ __launch_bounds__(256) void attn_mfma(const u16* __restrict__ qb,
                                                 const u16* __restrict__ kb,
                                                 const u16* __restrict__ vT,
                                                 const int* __restrict__ anchors,
                                                 const unsigned char* __restrict__ keep,
                                                 u16* __restrict__ attnb){
  int bx = blockIdx.x;
  int n = (bx & 1) ? (NBLK - 1 - (bx >> 1)) : (bx >> 1);   // heavy/light interleave (bijective)
  int h = blockIdx.y;
  int t = threadIdx.x, w = t >> 6, lane = t & 63;
  int g = lane >> 4, li = lane & 15;

  __shared__ __align__(16) u16 q_s[16][72];
  __shared__ __align__(16) u16 p_s[4][16][72];
  __shared__ float o_s[4][16][64];
  __shared__ float l_s[4][16];

  {
    int r = t >> 4, c4 = (t & 15) * 4;
    usv4 v = *(const usv4*)&qb[(size_t)(n * 16 + r) * DMODEL + h * 64 + c4];
    usv4 o;
    #pragma unroll
    for (int j = 0; j < 4; j++) o[j] = f2bf(bf2f(v[j]) * 0.125f);   // exact pow2 scale
    *(usv4*)&q_s[r][c4] = o;
  }
  __syncthreads();

  int anchor = anchors[n];
  bool kp = keep[n] != 0;
  const u16* kh  = kb + h * 64;
  const u16* vTh = vT + (size_t)(h * 64) * KVLEN;

  if (!kp){
    if (w == 0){
      float acc = 0.f;
      const u16* row = vTh + (size_t)lane * KVLEN;
      for (int k2 = 0; k2 < KVLEN; k2 += 8){
        short8 vv = *(const short8*)&row[k2];
        #pragma unroll
        for (int j = 0; j < 8; j++) acc += bf2f((u16)vv[j]);
      }
      acc *= (1.f / 4096.f);
      u16 ov = f2bf(acc);
      for (int r = 0; r < 16; r++)
        attnb[(size_t)(n * 16 + r) * DMODEL + h * 64 + lane] = ov;
    }
    return;
  }

  short8 qa[2];
  #pragma unroll
  for (int ks = 0; ks < 2; ks++)
    qa[ks] = *(const short8*)&q_s[li][ks * 32 + g * 8];

  int nctx = (anchor + 63) >> 6;
  int ntot = nctx + 1;

  f32x4 o_acc[4];
  float lp[4];                        // per-lane partial row sums (reduced once at end)
  #pragma unroll
  for (int i = 0; i < 4; i++){ o_acc[i] = (f32x4){0.f,0.f,0.f,0.f}; lp[i] = 0.f; }

  for (int c = w; c < ntot; c += 4){
    bool draft = (c == nctx);
    int kbase = draft ? (S_LEN + n * 16) : c * 64;
    int nk    = draft ? 16 : min(64, anchor - c * 64);

    f32x4 s[4];
    #pragma unroll
    for (int nf = 0; nf < 4; nf++) s[nf] = (f32x4){0.f,0.f,0.f,0.f};
    #pragma unroll
    for (int ks = 0; ks < 2; ks++){
      #pragma unroll
      for (int nf = 0; nf < 4; nf++){
        int krow = min(kbase + nf * 16 + li, KVLEN - 1);
        short8 bfrag = *(const short8*)&kh[(size_t)krow * DMODEL + ks * 32 + g * 8];
        s[nf] = __builtin_amdgcn_mfma_f32_16x16x32_bf16(qa[ks], bfrag, s[nf], 0, 0, 0);
      }
    }

    #pragma unroll
    for (int r = 0; r < 4; r++){
      #pragma unroll
      for (int nf = 0; nf < 4; nf++){
        float p = (nf * 16 + li < nk) ? __expf(s[nf][r]) : 0.f;
        lp[r] += p;
        p_s[w][g * 4 + r][nf * 16 + li] = f2bf(p);
      }
    }

    #pragma unroll
    for (int ks = 0; ks < 2; ks++){
      short8 pa = *(const short8*)&p_s[w][li][ks * 32 + g * 8];
      int kcol = min(kbase + ks * 32 + g * 8, KVLEN - 8);
      #pragma unroll
      for (int nfd = 0; nfd < 4; nfd++){
        short8 vfrag = *(const short8*)&vTh[(size_t)(nfd * 16 + li) * KVLEN + kcol];
        o_acc[nfd] = __builtin_amdgcn_mfma_f32_16x16x32_bf16(pa, vfrag, o_acc[nfd], 0, 0, 0);
      }
    }
  }

  // single deferred 16-lane reduce per row
  #pragma unroll
  for (int r = 0; r < 4; r++){
    float ps = lp[r];
    #pragma unroll
    for (int mm = 1; mm < 16; mm <<= 1) ps += __shfl_xor(ps, mm);
    if (li == 0) l_s[w][g * 4 + r] = ps;
    #pragma unroll
    for (int nfd = 0; nfd < 4; nfd++)
      o_s[w][g * 4 + r][nfd * 16 + li] = o_acc[nfd][r];
  }
  __syncthreads();

  {
    int row = t >> 4, c0 = (t & 15) * 4;
    float L = l_s[0][row] + l_s[1][row] + l_s[2][row] + l_s[3][row];
    float inv = 1.f / L;
    #pragma unroll
    for (int j = 0; j < 4; j++){
      float ov = o_s[0][row][c0 + j] + o_s[1][row][c0 + j] + o_s[2][row][c0 + j] + o_s[3][row][c0 + j];
      attnb[(size_t)(n * 16 + row) * DMODEL + h * 64 + c0 + j] = f2bf(ov * inv);
    }
  }
}

// ---------------- LM head (R13 config — empirical optimum) ----------------
__global__ __launch_bounds__(256) void lm_fused(const u16* __restrict__ obp,
                                                const u16* __restrict__ Wf,
                                                const int* __restrict__ input_ids,
                                                const int* __restrict__ anchors,
                                                float* __restrict__ pl,
                                                float* __restrict__ pt, float* __restrict__ pbv,
                                                int* __restrict__ pbi){
  __shared__ __align__(16) u16 Ob[2][128 * 64];
  __shared__ int tcol_s[128];

  int L = blockIdx.x;                       // 0..3999
  int T = (L & 7) * 500 + (L >> 3);         // bijective; XCD-contiguous T ranges
  int qbase = (T & 15) * 128;               // q fastest within an XCD -> W slice hot in its L2
  int vb = T >> 4;                          // 0..249 vocab block (128 wide)
  int vocabbase = vb * 128;
  int t = threadIdx.x, w = t >> 6, lane = t & 63;
  int g = lane >> 4, li = lane & 15;
  int wv = w & 1, wq = w >> 1;              // 2x2 wave grid

  if (t < 128){
    int r = qbase + t; int n = r >> 4, off = r & 15;
    int lab = anchors[n] + off;
    int safe = min(max(lab, 0), S_LEN - 1);
    tcol_s[t] = input_ids[safe];
  }

  int r0 = t >> 3, cg0 = t & 7;
  int swz = (cg0 ^ (r0 & 7)) << 3;
  auto stageO = [&](u16* odst, int kt){
    #pragma unroll
    for (int i = 0; i < 4; i++)
      __builtin_amdgcn_global_load_lds(GAS(&obp[(size_t)(qbase + r0 + i * 32) * DMODEL + kt * 64 + swz]),
                                       LAS(odst + i * 2048 + w * 512), 16, 0, 0);
  };
  const u16* wbase = Wf + ((size_t)(vb * 8 + wv * 4) * 16) * 512 + lane * 8;

  f32x4 acc[4][4];                          // [vf][qf]
  #pragma unroll
  for (int i = 0; i < 4; i++)
    #pragma unroll
    for (int j = 0; j < 4; j++)
      acc[i][j] = (f32x4){0.f, 0.f, 0.f, 0.f};

  stageO(Ob[0], 0);

  for (int kt = 0; kt < 8; kt++){
    const u16* curO = Ob[kt & 1];
    short8 wfr[2][4];
    if (kt < 7){
      stageO(Ob[(kt + 1) & 1], kt + 1);     // 4 vmem
      #pragma unroll
      for (int ks = 0; ks < 2; ks++)
        #pragma unroll
        for (int vf = 0; vf < 4; vf++)      // 8 vmem (direct global, L2-resident)
          wfr[ks][vf] = *(const short8*)(wbase + ((size_t)(vf * 16 + kt * 2 + ks) * 64) * 8);
      asm volatile("s_waitcnt vmcnt(12)" ::: "memory");  // stageO(kt) landed; 12 newer in flight
    } else {
      #pragma unroll
      for (int ks = 0; ks < 2; ks++)
        #pragma unroll
        for (int vf = 0; vf < 4; vf++)
          wfr[ks][vf] = *(const short8*)(wbase + ((size_t)(vf * 16 + kt * 2 + ks) * 64) * 8);
      asm volatile("s_waitcnt vmcnt(8)" ::: "memory");   // stageO(7) landed
    }
    __builtin_amdgcn_s_barrier();           // all waves: O(kt) visible
    __builtin_amdgcn_s_setprio(1);
    #pragma unroll
    for (int ks = 0; ks < 2; ks++){
      short8 obf[4];
      #pragma unroll
      for (int qf = 0; qf < 4; qf++)
        obf[qf] = *(const short8*)&curO[(wq * 64 + qf * 16 + li) * 64 + (((ks * 4 + g) ^ (li & 7)) << 3)];
      #pragma unroll
      for (int vf = 0; vf < 4; vf++)
        #pragma unroll
        for (int qf = 0; qf < 4; qf++)
          acc[vf][qf] = __builtin_amdgcn_mfma_f32_16x16x32_bf16(wfr[ks][vf], obf[qf], acc[vf][qf], 0, 0, 0);
    }
    __builtin_amdgcn_s_setprio(0);
    __builtin_amdgcn_s_barrier();           // all waves done reading Ob[kt&1]
  }
  __syncthreads();                          // before aliasing Ob as scratch

  float* cse = (float*)&Ob[0][0];           // [2][128]
  float* ctv = (float*)&Ob[0][512];
  float* cbv = (float*)&Ob[0][1024];
  int*   cbi = (int*)  &Ob[0][1536];

  #pragma unroll
  for (int qf = 0; qf < 4; qf++){
    int qloc = wq * 64 + qf * 16 + li;
    int tc = tcol_s[qloc] - (vocabbase + wv * 64);
    float se = 0.f, tv = -3e38f, bv = -3e38f; int bi = 0x7fffffff;
    #pragma unroll
    for (int vf = 0; vf < 4; vf++){
      #pragma unroll
      for (int r = 0; r < 4; r++){
        float v = acc[vf][qf][r];
        int pos = vf * 16 + g * 4 + r;
        se += __expf(v);
        if (pos == tc) tv = v;
        if (v > bv){ bv = v; bi = pos; }
      }
    }
    #pragma unroll
    for (int off = 16; off <= 32; off <<= 1){
      se += __shfl_xor(se, off);
      tv = fmaxf(tv, __shfl_xor(tv, off));
      float ob_ = __shfl_xor(bv, off); int oi = __shfl_xor(bi, off);
      if (ob_ > bv || (ob_ == bv && oi < bi)){ bv = ob_; bi = oi; }
    }
    if (g == 0){
      cse[wv * 128 + qloc] = se; ctv[wv * 128 + qloc] = tv;
      cbv[wv * 128 + qloc] = bv; cbi[wv * 128 + qloc] = wv * 64 + bi;
    }
  }
  __syncthreads();

  if (t < 128){
    float SE = 0.f, TV = -3e38f, BV = -3e38f; int BI = 0x7fffffff;
    #pragma unroll
    for (int vv = 0; vv < 2; vv++){
      SE += cse[vv * 128 + t];
      TV = fmaxf(TV, ctv[vv * 128 + t]);
      float v = cbv[vv * 128 + t];
      if (v > BV){ BV = v; BI = cbi[vv * 128 + t]; }  // vv ascends in vocab: strict > keeps first-max
    }
    size_t idx = (size_t)vb * QLEN + qbase + t;       // [split][row] -> coalesced
    pl[idx] = SE; pt[idx] = TV; pbv[idx] = BV; pbi[idx] = vocabbase + BI;
  }
}

// ---------------- per-row split merge ----------------
__global__ __launch_bounds__(256) void loss_rows(const float* __restrict__ pl,
                                                 const float* __restrict__ pt, const float* __restrict__ pbv,
                                                 const int* __restrict__ pbi,
                                                 const int* __restrict__ input_ids,
                                                 const int* __restrict__ anchors,
                                                 const unsigned char* __restrict__ keep,
                                                 const float* __restrict__ loss_mask,
                                                 float* __restrict__ rowacc){
  int t = threadIdx.x, w = t >> 6, lane = t & 63;
  int row = blockIdx.x * 4 + w;
  float L = 0.f, TV = -3e38f, BV = -3e38f; int BI = 0x7fffffff;
  for (int s = lane; s < NSPLIT; s += 64){
    size_t idx = (size_t)s * QLEN + row;    // [split][row]
    L += pl[idx];
    TV = fmaxf(TV, pt[idx]);
    float bv_ = pbv[idx]; int bi_ = pbi[idx];
    if (bv_ > BV || (bv_ == BV && bi_ < BI)){ BV = bv_; BI = bi_; }
  }
  #pragma unroll
  for (int mm = 1; mm < 64; mm <<= 1){
    L += __shfl_xor(L, mm);
    TV = fmaxf(TV, __shfl_xor(TV, mm));
    float ob = __shfl_xor(BV, mm); int oi = __shfl_xor(BI, mm);
    if (ob > BV || (ob == BV && oi < BI)){ BV = ob; BI = oi; }
  }
  if (lane == 0){
    int n = row >> 4, off = row & 15;
    int lab = anchors[n] + off;
    int valid = (lab < S_LEN) ? 1 : 0;
    int safe = min(max(lab, 0), S_LEN - 1);
    int tgt = input_ids[safe];
    float wgt = (keep[n] ? 1.f : 0.f) * (valid ? 1.f : 0.f) * ((off > 0) ? 1.f : 0.f) * loss_mask[safe];
    float logp = TV - __logf(L);
    rowacc[row * 3 + 0] = -logp * wgt;
    rowacc[row * 3 + 1] = wgt;
    rowacc[row * 3 + 2] = ((BI == tgt) && (wgt > 0.5f)) ? 1.f : 0.f;
  }
}

// ---------------- final sum over rows ----------------
__global__ __launch_bounds__(256) void final_sum(const float* __restrict__ rowacc, float* __restrict__ out){
  int t = threadIdx.x;
  float a = 0.f, b = 0.f, c = 0.f;
  for (int r = t; r < QLEN; r += 256){
    a += rowacc[r * 3 + 0]; b += rowacc[r * 3 + 1]; c += rowacc[r * 3 + 2];
  }
  __shared__ float sa[256], sb[256], sc_[256];
  sa[t] = a; sb[t] = b; sc_[t] = c;
  __syncthreads();
  for (int s = 128; s >= 1; s >>= 1){
    if (t < s){ sa[t] += sa[t + s]; sb[t] += sb[t + s]; sc_[t] += sc_[t + s]; }
    __syncthreads();
  }
  if (t == 0){
    out[0] = sa[0] / (sb[0] + 1e-6f);
    out[1] = sc_[0] / (sb[0] + 1e-6f);
  }
}

// ---------------- host ----------------
extern "C" void kernel_launch(void* const* d_in, const int* in_sizes, int n_in,
                              void* d_out, int out_size, void* d_ws, size_t ws_size,
                              hipStream_t stream) {
  const int*   input_ids = (const int*)  d_in[0];
  const float* hidden    = (const float*)d_in[1];
  const float* loss_mask = (const float*)d_in[2];
  const int*   anchors   = (const int*)  d_in[3];
  const unsigned char* keep = (const unsigned char*)d_in[4];
  const float* embed     = (const float*)d_in[5];
  const float* Wq        = (const float*)d_in[6];
  const float* Wk        = (const float*)d_in[7];
  const float* Wv        = (const float*)d_in[8];
  const float* Wo        = (const float*)d_in[9];
  const float* Wlm       = (const float*)d_in[10];

  char* ws = (char*)d_ws;
  size_t off = 0;
  auto take = [&](size_t bytes) -> char* {
    char* p = ws + off;
    off += (bytes + 255) & ~(size_t)255;
    return p;
  };
  u16* WqT  = (u16*)take((size_t)512 * 512 * 2);
  u16* WkT  = (u16*)take((size_t)512 * 512 * 2);
  u16* WvT  = (u16*)take((size_t)512 * 512 * 2);
  u16* WoT  = (u16*)take((size_t)512 * 512 * 2);
  u16* Wfrag= (u16*)take((size_t)VOCAB * 512 * 2);
  u16* kvb  = (u16*)take((size_t)KVLEN * 512 * 2);
  u16* qb2  = (u16*)take((size_t)QLEN * 512 * 2);
  u16* kb   = (u16*)take((size_t)KVLEN * 512 * 2);
  u16* vTb  = (u16*)take((size_t)512 * KVLEN * 2);
  u16* attnb= (u16*)take((size_t)QLEN * 512 * 2);
  u16* ob   = (u16*)take((size_t)QLEN * 512 * 2);
  float* pl = (float*)take((size_t)QLEN * NSPLIT * 4);
  float* pt = (float*)take((size_t)QLEN * NSPLIT * 4);
  float* pbv= (float*)take((size_t)QLEN * NSPLIT * 4);
  int*   pbi= (int*)  take((size_t)QLEN * NSPLIT * 4);
  float* rowacc = (float*)take((size_t)QLEN * 3 * 4);

  prep_all<<<11072, 256, 0, stream>>>(Wq, Wk, Wv, Wo, Wlm, hidden, embed, input_ids, anchors, keep,
                                      WqT, WkT, WvT, WoT, Wfrag, kvb);

  qkv_gemm<<<640, 256, 0, stream>>>(kvb, WkT, WvT, WqT, kb, vTb, qb2);

  attn_mfma<<<dim3(NBLK, 8), 256, 0, stream>>>(qb2, kb, vTb, anchors, keep, attnb);

  gemmO<<<dim3(32, 8), 256, 0, stream>>>(attnb, WoT, ob);

  lm_fused<<<4000, 256, 0, stream>>>(ob, Wfrag, input_ids, anchors, pl, pt, pbv, pbi);

  loss_rows<<<512, 256, 0, stream>>>(pl, pt, pbv, pbi, input_ids, anchors, keep, loss_mask, rowacc);

  final_sum<<<1, 256, 0, stream>>>(rowacc, (float*)d_out);
}